// Round 9
// baseline (128.594 us; speedup 1.0000x reference)
//
#include <hip/hip_runtime.h>
#include <hip/hip_bf16.h>

// ContrastiveLoss: B=8192, D=128, 100 classes.
// loss_i = -log( max(sum_{j!=i, lab_j==lab_i} e^{s_ij},1e-8) / max(sum_{j!=i} e^{s_ij},1e-8) )
// s_ij = clip( f_hat_i . f_hat_j / 0.07, -10, 10 );  out = mean_i loss_i
//
// fb = f_hat * sqrt(log2e/0.07) in bf16 -> MFMA dot yields s/0.07*log2e directly;
// clamp at +-10*log2e (fmed3), single v_exp_f32 (exp2). Diagonal excluded exactly
// via wave-uniform tile check.
//
// R8: R7 (32 KB LDS) regressed because LDS-limited occupancy = 5 blocks/CU ->
// RA register cap 512/5 ~= 102 < ~108 live -> slight spill across 2048 blocks.
// Fix: pad LDS to exactly 40 KB (160 rows, use 128) -> 4 blocks/CU -> cap 128
// -> no spill, and we still get 4 waves/SIMD (2x R6's latency hiding).
// Occupancy is a step function of (RA cap >= demand): 64KB/2blk=cap256 OK,
// 40KB/4blk=cap128 OK, 32KB/5blk=cap102 SPILLS, 512thr=cap64 DISASTER.

using short8  = __attribute__((ext_vector_type(8))) short;   // 8 bf16 = 4 VGPRs
using floatx4 = __attribute__((ext_vector_type(4))) float;

constexpr int   Bn = 8192;
constexpr int   Dk = 128;
constexpr int   NSLICE = 64;               // j-slices (blockIdx.x), 128 cols each
constexpr float PRESCALE = 4.5398160f;     // sqrt(log2(e)/0.07)
constexpr float CLAMP    = 14.4269504f;    // 10*log2(e)
constexpr float LN2      = 0.69314718056f;

// ---- kernel 1: row L2-normalize, scale, cast to bf16; also zero `out` ----
__global__ __launch_bounds__(256) void normalize_k(
    const float* __restrict__ feat, unsigned short* __restrict__ fb,
    float* __restrict__ out) {
  if (blockIdx.x == 0 && threadIdx.x == 0) *out = 0.f;   // replaces memset dispatch
  const int row  = blockIdx.x * 4 + (threadIdx.x >> 6);
  const int lane = threadIdx.x & 63;
  const float2 v = ((const float2*)(feat + (size_t)row * Dk))[lane];
  float s = v.x * v.x + v.y * v.y;
#pragma unroll
  for (int m = 1; m < 64; m <<= 1) s += __shfl_xor(s, m);
  const float inv = PRESCALE / fmaxf(sqrtf(s), 1e-8f);
  __hip_bfloat16 b0 = __float2bfloat16(v.x * inv);
  __hip_bfloat16 b1 = __float2bfloat16(v.y * inv);
  ushort2 o;
  o.x = __builtin_bit_cast(unsigned short, b0);
  o.y = __builtin_bit_cast(unsigned short, b1);
  ((ushort2*)(fb + (size_t)row * Dk))[lane] = o;
}

// ---- kernel 2: tiled F*F^T with fused exp + masked row-sum --------------
// grid: (64 j-slices, 32 i-blocks). Block = 256 thr = 4 waves, 40 KB LDS
// (32 KB used + 8 KB pad to pin occupancy at exactly 4 blocks/CU).
// Block stages its 128-col B panel in LDS once; each wave covers 64 rows as
// two sequential 32-row passes x 128 cols (8 col-tiles of 16).
__global__ __launch_bounds__(256, 4) void simloss_k(
    const unsigned short* __restrict__ fb, const int* __restrict__ labels,
    float* __restrict__ rowpos2, float* __restrict__ rowneg2) {
  // 160 rows x 128 shorts = 40960 B; only rows [0,128) are used. The extra
  // 8 KB pins LDS-limited occupancy to 4 blocks/CU (160/40) so the RA's
  // register cap is 512/4 = 128 >= ~108 live regs -> no spill.
  __shared__ __align__(16) short Bsh[160 * Dk];

  const int t     = threadIdx.x;
  const int lane  = t & 63;
  const int wave  = t >> 6;                         // [0,4)
  const int quad  = lane >> 4;
  const int lr    = lane & 15;
  const int jbase = blockIdx.x * 128;               // cols [jbase, jbase+128)

  // ---- stage B panel into LDS, swizzled: chunk c of row r -> c ^ (r&7) ----
  {
    const int chunk = t & 15;        // 16B chunk within a 256B row
    const int r0    = t >> 4;        // [0,16)
#pragma unroll
    for (int it = 0; it < 8; ++it) {
      const int row = r0 + it * 16;
      const short8 v = *(const short8*)((const short*)fb +
                          (size_t)(jbase + row) * Dk + chunk * 8);
      *(short8*)(Bsh + row * Dk + ((chunk ^ (row & 7)) * 8)) = v;
    }
  }

  // column labels for this lane, packed 2 tiles per reg (labels < 100 fit u16)
  int labj16[4];
#pragma unroll
  for (int j = 0; j < 4; ++j) {
    const int l0 = labels[jbase + (2 * j) * 16 + lr];
    const int l1 = labels[jbase + (2 * j + 1) * 16 + lr];
    labj16[j] = l0 | (l1 << 16);
  }

  bool dl[4];
#pragma unroll
  for (int r = 0; r < 4; ++r) dl[r] = (quad * 4 + r) == lr;

  // per-lane swizzled chunk offsets (constant across jt), in shorts
  const int sw = lr & 7;
  const int c0 = ((0 + quad) ^ sw) * 8;
  const int c1 = ((4 + quad) ^ sw) * 8;
  const int c2 = ((8 + quad) ^ sw) * 8;
  const int c3 = ((12 + quad) ^ sw) * 8;

  __syncthreads();

#pragma unroll 1
  for (int p = 0; p < 2; ++p) {
    // rows [ibase, ibase+32) this pass; wave covers 64 rows total
    const int ibase = blockIdx.y * 256 + wave * 64 + p * 32;

    // A fragments (proven no-spill shape: 32 VGPRs, loaded per pass)
    short8 A[2][4];
#pragma unroll
    for (int tt = 0; tt < 2; ++tt) {
      const short* ap = (const short*)fb + (size_t)(ibase + tt * 16 + lr) * Dk + quad * 8;
#pragma unroll
      for (int kk = 0; kk < 4; ++kk) A[tt][kk] = *(const short8*)(ap + kk * 32);
    }

    // row labels (accumulator rows: row_in_tile = quad*4 + r)
    int li[2][4];
#pragma unroll
    for (int tt = 0; tt < 2; ++tt)
#pragma unroll
      for (int r = 0; r < 4; ++r)
        li[tt][r] = labels[ibase + tt * 16 + quad * 4 + r];

    float pos[2][4] = {};
    float neg[2][4] = {};

#pragma unroll
    for (int jt = 0; jt < 8; ++jt) {
      const short* bp = Bsh + (jt * 16 + lr) * Dk;
      const short8 B0 = *(const short8*)(bp + c0);
      const short8 B1 = *(const short8*)(bp + c1);
      const short8 B2 = *(const short8*)(bp + c2);
      const short8 B3 = *(const short8*)(bp + c3);

      floatx4 acc0 = {0.f, 0.f, 0.f, 0.f};
      floatx4 acc1 = {0.f, 0.f, 0.f, 0.f};
      acc0 = __builtin_amdgcn_mfma_f32_16x16x32_bf16(A[0][0], B0, acc0, 0, 0, 0);
      acc1 = __builtin_amdgcn_mfma_f32_16x16x32_bf16(A[1][0], B0, acc1, 0, 0, 0);
      acc0 = __builtin_amdgcn_mfma_f32_16x16x32_bf16(A[0][1], B1, acc0, 0, 0, 0);
      acc1 = __builtin_amdgcn_mfma_f32_16x16x32_bf16(A[1][1], B1, acc1, 0, 0, 0);
      acc0 = __builtin_amdgcn_mfma_f32_16x16x32_bf16(A[0][2], B2, acc0, 0, 0, 0);
      acc1 = __builtin_amdgcn_mfma_f32_16x16x32_bf16(A[1][2], B2, acc1, 0, 0, 0);
      acc0 = __builtin_amdgcn_mfma_f32_16x16x32_bf16(A[0][3], B3, acc0, 0, 0, 0);
      acc1 = __builtin_amdgcn_mfma_f32_16x16x32_bf16(A[1][3], B3, acc1, 0, 0, 0);

      const int j0 = jbase + jt * 16;
      const int lj = (jt & 1) ? (labj16[jt >> 1] >> 16) : (labj16[jt >> 1] & 0xffff);
      float e0, e1, e2, e3;
      // tile t=0
      e0 = __builtin_amdgcn_exp2f(__builtin_amdgcn_fmed3f(acc0[0], -CLAMP, CLAMP));
      e1 = __builtin_amdgcn_exp2f(__builtin_amdgcn_fmed3f(acc0[1], -CLAMP, CLAMP));
      e2 = __builtin_amdgcn_exp2f(__builtin_amdgcn_fmed3f(acc0[2], -CLAMP, CLAMP));
      e3 = __builtin_amdgcn_exp2f(__builtin_amdgcn_fmed3f(acc0[3], -CLAMP, CLAMP));
      if (j0 == ibase) {                 // wave-uniform: tile on diagonal
        if (dl[0]) e0 = 0.f;
        if (dl[1]) e1 = 0.f;
        if (dl[2]) e2 = 0.f;
        if (dl[3]) e3 = 0.f;
      }
      neg[0][0] += e0; neg[0][1] += e1; neg[0][2] += e2; neg[0][3] += e3;
      pos[0][0] += (li[0][0] == lj) ? e0 : 0.f;
      pos[0][1] += (li[0][1] == lj) ? e1 : 0.f;
      pos[0][2] += (li[0][2] == lj) ? e2 : 0.f;
      pos[0][3] += (li[0][3] == lj) ? e3 : 0.f;
      // tile t=1
      e0 = __builtin_amdgcn_exp2f(__builtin_amdgcn_fmed3f(acc1[0], -CLAMP, CLAMP));
      e1 = __builtin_amdgcn_exp2f(__builtin_amdgcn_fmed3f(acc1[1], -CLAMP, CLAMP));
      e2 = __builtin_amdgcn_exp2f(__builtin_amdgcn_fmed3f(acc1[2], -CLAMP, CLAMP));
      e3 = __builtin_amdgcn_exp2f(__builtin_amdgcn_fmed3f(acc1[3], -CLAMP, CLAMP));
      if (j0 == ibase + 16) {
        if (dl[0]) e0 = 0.f;
        if (dl[1]) e1 = 0.f;
        if (dl[2]) e2 = 0.f;
        if (dl[3]) e3 = 0.f;
      }
      neg[1][0] += e0; neg[1][1] += e1; neg[1][2] += e2; neg[1][3] += e3;
      pos[1][0] += (li[1][0] == lj) ? e0 : 0.f;
      pos[1][1] += (li[1][1] == lj) ? e1 : 0.f;
      pos[1][2] += (li[1][2] == lj) ? e2 : 0.f;
      pos[1][3] += (li[1][3] == lj) ? e3 : 0.f;
    }

    // reduce across the 16 lanes of a col-group (xor 1,2,4,8 stays in group);
    // unique (slice,row) writer -> plain stores, no atomics, no memset
#pragma unroll
    for (int tt = 0; tt < 2; ++tt)
#pragma unroll
      for (int r = 0; r < 4; ++r) {
        float p2 = pos[tt][r], n2 = neg[tt][r];
#pragma unroll
        for (int m = 1; m < 16; m <<= 1) {
          p2 += __shfl_xor(p2, m);
          n2 += __shfl_xor(n2, m);
        }
        if (lr == 0) {
          const int row = ibase + tt * 16 + quad * 4 + r;
          rowpos2[(size_t)blockIdx.x * Bn + row] = p2;
          rowneg2[(size_t)blockIdx.x * Bn + row] = n2;
        }
      }

    __builtin_amdgcn_sched_barrier(0);   // keep pass-1 A-loads from hoisting
  }
}

// ---- kernel 3: sum slice partials, per-row loss, mean (distributed) ------
__global__ __launch_bounds__(256) void finalize_k(
    const float* __restrict__ rowpos2, const float* __restrict__ rowneg2,
    float* __restrict__ out) {
  const int row = blockIdx.x * 256 + threadIdx.x;
  float p = 0.f, n = 0.f;
#pragma unroll
  for (int s = 0; s < NSLICE; ++s) {       // coalesced: consecutive rows adjacent
    p += rowpos2[(size_t)s * Bn + row];
    n += rowneg2[(size_t)s * Bn + row];
  }
  p = fmaxf(p, 1e-8f);
  n = fmaxf(n, 1e-8f);
  float loss = LN2 * (__builtin_amdgcn_logf(n) - __builtin_amdgcn_logf(p));
#pragma unroll
  for (int m = 1; m < 64; m <<= 1) loss += __shfl_xor(loss, m);
  __shared__ float partial[4];
  const int lane = threadIdx.x & 63, w = threadIdx.x >> 6;
  if (lane == 0) partial[w] = loss;
  __syncthreads();
  if (threadIdx.x == 0) {
    const float s = partial[0] + partial[1] + partial[2] + partial[3];
    atomicAdd(out, s * (1.0f / (float)Bn));   // out zeroed by normalize_k
  }
}

extern "C" void kernel_launch(void* const* d_in, const int* in_sizes, int n_in,
                              void* d_out, int out_size, void* d_ws, size_t ws_size,
                              hipStream_t stream) {
  const float* feat   = (const float*)d_in[0];
  const int*   labels = (const int*)d_in[1];
  float* out = (float*)d_out;

  // ws layout: [0, 2MB) bf16 fb[8192][128]; then rowpos2[64][8192], rowneg2[64][8192]
  unsigned short* fb = (unsigned short*)d_ws;
  float* rowpos2 = (float*)((char*)d_ws + (size_t)Bn * Dk * sizeof(unsigned short));
  float* rowneg2 = rowpos2 + (size_t)NSLICE * Bn;

  normalize_k<<<Bn / 4, 256, 0, stream>>>(feat, fb, out);
  dim3 grid(NSLICE, 32);  // x = j-slice (128 cols), y = i-block (256 rows)
  simloss_k<<<grid, 256, 0, stream>>>(fb, labels, rowpos2, rowneg2);
  finalize_k<<<Bn / 256, 256, 0, stream>>>(rowpos2, rowneg2, out);
}

// Round 10
// 102.527 us; speedup vs baseline: 1.2542x; 1.2542x over previous
//
#include <hip/hip_runtime.h>
#include <hip/hip_bf16.h>

// ContrastiveLoss: B=8192, D=128, 100 classes.
// loss_i = -log( max(sum_{j!=i, lab_j==lab_i} e^{s_ij},1e-8) / max(sum_{j!=i} e^{s_ij},1e-8) )
// s_ij = clip( f_hat_i . f_hat_j / 0.07, -10, 10 );  out = mean_i loss_i
//
// fb = f_hat * sqrt(log2e/0.07) in FP8 e4m3 -> MFMA dot yields s/0.07*log2e;
// clamp +-10*log2e (fmed3), one v_exp_f32. Diagonal zeroed exactly (wave-
// uniform tile check). fp8 error: dot sigma~0.005 -> log-sum error ~0.008,
// 10x under the 9.25e-2 threshold; exp convexity bias cancels in pos/neg.
//
// R9: LDS read bandwidth identified as the binding pipe (537 MB of b128 reads
// ~10us + 2.1M bank conflicts; VALU ~8.5us hides under it). fp8 halves LDS
// bytes/sim (8->4) and staging, and cuts A-frag registers 32->16 (demand ~80
// < the launch_bounds(256,2) RA cap of 128 -> no spill; R8 proved (256,4)
// pinches the cap to 64 and spills). fb stored k-PERMUTED so each lane's 4
// MFMA operands are 32 contiguous bytes = 2 ds_read_b128 per jt.

using floatx4 = __attribute__((ext_vector_type(4))) float;
using llong2  = __attribute__((ext_vector_type(2))) long long;

constexpr int   Bn = 8192;
constexpr int   Dk = 128;                  // bytes per fp8 row
constexpr int   NSLICE = 32;               // j-slices (blockIdx.x), 256 cols each
constexpr float PRESCALE = 4.5398160f;     // sqrt(log2(e)/0.07)
constexpr float CLAMP    = 14.4269504f;    // 10*log2(e)
constexpr float LN2      = 0.69314718056f;

// ---- kernel 1: L2-normalize, scale, cast fp8, k-permuted store; zero out --
// permutation: byte position p(k) = ((k%32)/8)*32 + (k/32)*8 + (k%8), so a
// lane's MFMA operands (k = m*32 + quad*8 + j, m=0..3) are 32 contiguous
// bytes at offset quad*32.
__global__ __launch_bounds__(256) void normalize_k(
    const float* __restrict__ feat, unsigned char* __restrict__ fb,
    float* __restrict__ out) {
  if (blockIdx.x == 0 && threadIdx.x == 0) *out = 0.f;
  const int row  = blockIdx.x * 4 + (threadIdx.x >> 6);
  const int lane = threadIdx.x & 63;
  const float2 v = ((const float2*)(feat + (size_t)row * Dk))[lane];
  float s = v.x * v.x + v.y * v.y;
#pragma unroll
  for (int m = 1; m < 64; m <<= 1) s += __shfl_xor(s, m);
  const float inv = PRESCALE / fmaxf(sqrtf(s), 1e-8f);
  const int packed = __builtin_amdgcn_cvt_pk_fp8_f32(v.x * inv, v.y * inv, 0, false);
  const int k0 = 2 * lane;   // k0 even -> both bytes land adjacent after permute
  const int p  = ((k0 & 31) >> 3) * 32 + (k0 >> 5) * 8 + (k0 & 7);
  *(unsigned short*)(fb + (size_t)row * Dk + p) = (unsigned short)(packed & 0xffff);
}

// ---- kernel 2: tiled F*F^T with fused exp + masked row-sum --------------
// grid: (32 j-slices, 32 i-blocks). Block = 256 thr = 4 waves, 32 KB LDS.
// Block stages its 256-col fp8 B panel (XOR-16B-chunk swizzle); each wave
// covers 64 rows as two sequential 32-row passes x 256 cols (16 tiles).
__global__ __launch_bounds__(256, 2) void simloss_k(
    const unsigned char* __restrict__ fb, const int* __restrict__ labels,
    float* __restrict__ rowpos2, float* __restrict__ rowneg2) {
  __shared__ __align__(16) unsigned char Bsh[256 * Dk];   // 32768 B

  const int t     = threadIdx.x;
  const int lane  = t & 63;
  const int wave  = t >> 6;                         // [0,4)
  const int quad  = lane >> 4;
  const int lr    = lane & 15;
  const int jbase = blockIdx.x * 256;               // cols [jbase, jbase+256)

  // ---- stage B panel: 16B chunk c of row r -> LDS chunk c ^ (r&7) --------
  {
    const int chunk = t & 7;         // 16B chunk within a 128B row
    const int r0    = t >> 3;        // [0,32)
#pragma unroll
    for (int it = 0; it < 8; ++it) {
      const int row = r0 + it * 32;
      const llong2 v = *(const llong2*)(fb + (size_t)(jbase + row) * Dk + chunk * 16);
      *(llong2*)(Bsh + row * Dk + ((chunk ^ (row & 7)) * 16)) = v;
    }
  }

  // column labels for this lane, packed 2 tiles per reg (labels < 100 fit u16)
  int labj16[8];
#pragma unroll
  for (int j = 0; j < 8; ++j) {
    const int l0 = labels[jbase + (2 * j) * 16 + lr];
    const int l1 = labels[jbase + (2 * j + 1) * 16 + lr];
    labj16[j] = l0 | (l1 << 16);
  }

  bool dl[4];
#pragma unroll
  for (int r = 0; r < 4; ++r) dl[r] = (quad * 4 + r) == lr;

  // per-lane swizzled 16B-chunk offsets (constant across jt), in bytes
  const int sw  = lr & 7;
  const int ch0 = ((quad * 2)     ^ sw) * 16;   // MFMA operands m=0,1
  const int ch1 = ((quad * 2 + 1) ^ sw) * 16;   // MFMA operands m=2,3

  __syncthreads();

#pragma unroll 1
  for (int p = 0; p < 2; ++p) {
    // rows [ibase, ibase+32) this pass; wave covers 64 rows total
    const int ibase = blockIdx.y * 256 + wave * 64 + p * 32;

    // A fragments: per row-tile 32 contiguous bytes (permuted layout) = 2x16B
    llong2 A0lo, A0hi, A1lo, A1hi;
    {
      const unsigned char* ap0 = fb + (size_t)(ibase + lr) * Dk + quad * 32;
      const unsigned char* ap1 = ap0 + 16 * Dk;
      A0lo = *(const llong2*)(ap0);       // m=0 (.x), m=1 (.y)
      A0hi = *(const llong2*)(ap0 + 16);  // m=2, m=3
      A1lo = *(const llong2*)(ap1);
      A1hi = *(const llong2*)(ap1 + 16);
    }

    // row labels (accumulator rows: row_in_tile = quad*4 + r)
    int li[2][4];
#pragma unroll
    for (int tt = 0; tt < 2; ++tt)
#pragma unroll
      for (int r = 0; r < 4; ++r)
        li[tt][r] = labels[ibase + tt * 16 + quad * 4 + r];

    float pos[2][4] = {};
    float neg[2][4] = {};

#pragma unroll
    for (int jt = 0; jt < 16; ++jt) {
      const unsigned char* bp = Bsh + (jt * 16 + lr) * Dk;
      const llong2 Blo = *(const llong2*)(bp + ch0);   // m=0,1
      const llong2 Bhi = *(const llong2*)(bp + ch1);   // m=2,3

      floatx4 acc0 = {0.f, 0.f, 0.f, 0.f};
      floatx4 acc1 = {0.f, 0.f, 0.f, 0.f};
      acc0 = __builtin_amdgcn_mfma_f32_16x16x32_fp8_fp8(A0lo.x, Blo.x, acc0, 0, 0, 0);
      acc1 = __builtin_amdgcn_mfma_f32_16x16x32_fp8_fp8(A1lo.x, Blo.x, acc1, 0, 0, 0);
      acc0 = __builtin_amdgcn_mfma_f32_16x16x32_fp8_fp8(A0lo.y, Blo.y, acc0, 0, 0, 0);
      acc1 = __builtin_amdgcn_mfma_f32_16x16x32_fp8_fp8(A1lo.y, Blo.y, acc1, 0, 0, 0);
      acc0 = __builtin_amdgcn_mfma_f32_16x16x32_fp8_fp8(A0hi.x, Bhi.x, acc0, 0, 0, 0);
      acc1 = __builtin_amdgcn_mfma_f32_16x16x32_fp8_fp8(A1hi.x, Bhi.x, acc1, 0, 0, 0);
      acc0 = __builtin_amdgcn_mfma_f32_16x16x32_fp8_fp8(A0hi.y, Bhi.y, acc0, 0, 0, 0);
      acc1 = __builtin_amdgcn_mfma_f32_16x16x32_fp8_fp8(A1hi.y, Bhi.y, acc1, 0, 0, 0);

      const int j0 = jbase + jt * 16;
      const int lj = (jt & 1) ? (labj16[jt >> 1] >> 16) : (labj16[jt >> 1] & 0xffff);
      float e0, e1, e2, e3;
      // tile t=0
      e0 = __builtin_amdgcn_exp2f(__builtin_amdgcn_fmed3f(acc0[0], -CLAMP, CLAMP));
      e1 = __builtin_amdgcn_exp2f(__builtin_amdgcn_fmed3f(acc0[1], -CLAMP, CLAMP));
      e2 = __builtin_amdgcn_exp2f(__builtin_amdgcn_fmed3f(acc0[2], -CLAMP, CLAMP));
      e3 = __builtin_amdgcn_exp2f(__builtin_amdgcn_fmed3f(acc0[3], -CLAMP, CLAMP));
      if (j0 == ibase) {                 // wave-uniform: tile on diagonal
        if (dl[0]) e0 = 0.f;
        if (dl[1]) e1 = 0.f;
        if (dl[2]) e2 = 0.f;
        if (dl[3]) e3 = 0.f;
      }
      neg[0][0] += e0; neg[0][1] += e1; neg[0][2] += e2; neg[0][3] += e3;
      pos[0][0] += (li[0][0] == lj) ? e0 : 0.f;
      pos[0][1] += (li[0][1] == lj) ? e1 : 0.f;
      pos[0][2] += (li[0][2] == lj) ? e2 : 0.f;
      pos[0][3] += (li[0][3] == lj) ? e3 : 0.f;
      // tile t=1
      e0 = __builtin_amdgcn_exp2f(__builtin_amdgcn_fmed3f(acc1[0], -CLAMP, CLAMP));
      e1 = __builtin_amdgcn_exp2f(__builtin_amdgcn_fmed3f(acc1[1], -CLAMP, CLAMP));
      e2 = __builtin_amdgcn_exp2f(__builtin_amdgcn_fmed3f(acc1[2], -CLAMP, CLAMP));
      e3 = __builtin_amdgcn_exp2f(__builtin_amdgcn_fmed3f(acc1[3], -CLAMP, CLAMP));
      if (j0 == ibase + 16) {
        if (dl[0]) e0 = 0.f;
        if (dl[1]) e1 = 0.f;
        if (dl[2]) e2 = 0.f;
        if (dl[3]) e3 = 0.f;
      }
      neg[1][0] += e0; neg[1][1] += e1; neg[1][2] += e2; neg[1][3] += e3;
      pos[1][0] += (li[1][0] == lj) ? e0 : 0.f;
      pos[1][1] += (li[1][1] == lj) ? e1 : 0.f;
      pos[1][2] += (li[1][2] == lj) ? e2 : 0.f;
      pos[1][3] += (li[1][3] == lj) ? e3 : 0.f;
    }

    // reduce across the 16 lanes of a col-group (xor 1,2,4,8 stays in group);
    // unique (slice,row) writer -> plain stores, no atomics, no memset
#pragma unroll
    for (int tt = 0; tt < 2; ++tt)
#pragma unroll
      for (int r = 0; r < 4; ++r) {
        float p2 = pos[tt][r], n2 = neg[tt][r];
#pragma unroll
        for (int m = 1; m < 16; m <<= 1) {
          p2 += __shfl_xor(p2, m);
          n2 += __shfl_xor(n2, m);
        }
        if (lr == 0) {
          const int row = ibase + tt * 16 + quad * 4 + r;
          rowpos2[(size_t)blockIdx.x * Bn + row] = p2;
          rowneg2[(size_t)blockIdx.x * Bn + row] = n2;
        }
      }

    __builtin_amdgcn_sched_barrier(0);   // keep pass-1 A-loads from hoisting
  }
}

// ---- kernel 3: sum slice partials, per-row loss, mean (distributed) ------
__global__ __launch_bounds__(256) void finalize_k(
    const float* __restrict__ rowpos2, const float* __restrict__ rowneg2,
    float* __restrict__ out) {
  const int row = blockIdx.x * 256 + threadIdx.x;
  float p = 0.f, n = 0.f;
#pragma unroll
  for (int s = 0; s < NSLICE; ++s) {       // coalesced: consecutive rows adjacent
    p += rowpos2[(size_t)s * Bn + row];
    n += rowneg2[(size_t)s * Bn + row];
  }
  p = fmaxf(p, 1e-8f);
  n = fmaxf(n, 1e-8f);
  float loss = LN2 * (__builtin_amdgcn_logf(n) - __builtin_amdgcn_logf(p));
#pragma unroll
  for (int m = 1; m < 64; m <<= 1) loss += __shfl_xor(loss, m);
  __shared__ float partial[4];
  const int lane = threadIdx.x & 63, w = threadIdx.x >> 6;
  if (lane == 0) partial[w] = loss;
  __syncthreads();
  if (threadIdx.x == 0) {
    const float s = partial[0] + partial[1] + partial[2] + partial[3];
    atomicAdd(out, s * (1.0f / (float)Bn));   // out zeroed by normalize_k
  }
}

extern "C" void kernel_launch(void* const* d_in, const int* in_sizes, int n_in,
                              void* d_out, int out_size, void* d_ws, size_t ws_size,
                              hipStream_t stream) {
  const float* feat   = (const float*)d_in[0];
  const int*   labels = (const int*)d_in[1];
  float* out = (float*)d_out;

  // ws layout: [0, 1MB) fp8 fb[8192][128]; then rowpos2[32][8192], rowneg2[32][8192]
  unsigned char* fb = (unsigned char*)d_ws;
  float* rowpos2 = (float*)((char*)d_ws + (size_t)Bn * Dk);
  float* rowneg2 = rowpos2 + (size_t)NSLICE * Bn;

  normalize_k<<<Bn / 4, 256, 0, stream>>>(feat, fb, out);
  dim3 grid(NSLICE, 32);  // x = j-slice (256 cols), y = i-block (256 rows)
  simloss_k<<<grid, 256, 0, stream>>>(fb, labels, rowpos2, rowneg2);
  finalize_k<<<Bn / 256, 256, 0, stream>>>(rowpos2, rowneg2, out);
}

// Round 11
// 99.489 us; speedup vs baseline: 1.2925x; 1.0305x over previous
//
#include <hip/hip_runtime.h>
#include <hip/hip_bf16.h>

// ContrastiveLoss: B=8192, D=128, 100 classes.
// loss_i = -log( max(sum_{j!=i, lab_j==lab_i} e^{s_ij},1e-8) / max(sum_{j!=i} e^{s_ij},1e-8) )
// s_ij = clip( f_hat_i . f_hat_j / 0.07, -10, 10 );  out = mean_i loss_i
//
// fb = f_hat * sqrt(log2e/0.07) in FP8 e4m3 -> MFMA dot yields s/0.07*log2e;
// clamp +-10*log2e (fmed3), one v_exp_f32. Diagonal zeroed exactly (wave-
// uniform tile check). fp8 dot error sigma~0.005 -> log-sum error ~0.008,
// 10x under the 9.25e-2 threshold.
//
// R10: swap 8x mfma_f32_16x16x32_fp8_fp8 (runs at bf16 rate, 2047 TF) for
// 2x mfma_scale_f32_16x16x128_f8f6f4 with identity scales (0x7F E8M0 per
// 32-block) — the MX path is 2x rate (4661 TF) and one inst covers all of
// K=128. The scaled operand layout is four stacked K=32 sub-operands
// (reg-pair m: k = m*32 + quad*8 + j) — exactly what R9's k-permuted fb
// already provides, so staging/epilogue are unchanged. MFMA pipe 8.4->3.7us,
// dep chain 4->2.

using floatx4 = __attribute__((ext_vector_type(4))) float;
using intx4   = __attribute__((ext_vector_type(4))) int;
using intx8   = __attribute__((ext_vector_type(8))) int;
using llong2  = __attribute__((ext_vector_type(2))) long long;

constexpr int   Bn = 8192;
constexpr int   Dk = 128;                  // bytes per fp8 row
constexpr int   NSLICE = 32;               // j-slices (blockIdx.x), 256 cols each
constexpr float PRESCALE = 4.5398160f;     // sqrt(log2(e)/0.07)
constexpr float CLAMP    = 14.4269504f;    // 10*log2(e)
constexpr float LN2      = 0.69314718056f;
constexpr int   SCALE1   = 0x7F7F7F7F;     // identity E8M0 scale for 4 k-blocks

// ---- kernel 1: L2-normalize, scale, cast fp8, k-permuted store; zero out --
// permutation: byte position p(k) = ((k%32)/8)*32 + (k/32)*8 + (k%8), so a
// lane's MFMA operands (k = m*32 + quad*8 + j, m=0..3) are 32 contiguous
// bytes at offset quad*32 (matches the f8f6f4 stacked-K=32 operand layout).
__global__ __launch_bounds__(256) void normalize_k(
    const float* __restrict__ feat, unsigned char* __restrict__ fb,
    float* __restrict__ out) {
  if (blockIdx.x == 0 && threadIdx.x == 0) *out = 0.f;
  const int row  = blockIdx.x * 4 + (threadIdx.x >> 6);
  const int lane = threadIdx.x & 63;
  const float2 v = ((const float2*)(feat + (size_t)row * Dk))[lane];
  float s = v.x * v.x + v.y * v.y;
#pragma unroll
  for (int m = 1; m < 64; m <<= 1) s += __shfl_xor(s, m);
  const float inv = PRESCALE / fmaxf(sqrtf(s), 1e-8f);
  const int packed = __builtin_amdgcn_cvt_pk_fp8_f32(v.x * inv, v.y * inv, 0, false);
  const int k0 = 2 * lane;   // k0 even -> both bytes land adjacent after permute
  const int p  = ((k0 & 31) >> 3) * 32 + (k0 >> 5) * 8 + (k0 & 7);
  *(unsigned short*)(fb + (size_t)row * Dk + p) = (unsigned short)(packed & 0xffff);
}

// ---- kernel 2: tiled F*F^T with fused exp + masked row-sum --------------
// grid: (32 j-slices, 32 i-blocks). Block = 256 thr = 4 waves, 32 KB LDS.
// Block stages its 256-col fp8 B panel (XOR-16B-chunk swizzle); each wave
// covers 64 rows as two sequential 32-row passes x 256 cols (16 tiles).
__global__ __launch_bounds__(256, 2) void simloss_k(
    const unsigned char* __restrict__ fb, const int* __restrict__ labels,
    float* __restrict__ rowpos2, float* __restrict__ rowneg2) {
  __shared__ __align__(16) unsigned char Bsh[256 * Dk];   // 32768 B

  const int t     = threadIdx.x;
  const int lane  = t & 63;
  const int wave  = t >> 6;                         // [0,4)
  const int quad  = lane >> 4;
  const int lr    = lane & 15;
  const int jbase = blockIdx.x * 256;               // cols [jbase, jbase+256)

  // ---- stage B panel: 16B chunk c of row r -> LDS chunk c ^ (r&7) --------
  {
    const int chunk = t & 7;         // 16B chunk within a 128B row
    const int r0    = t >> 3;        // [0,32)
#pragma unroll
    for (int it = 0; it < 8; ++it) {
      const int row = r0 + it * 32;
      const llong2 v = *(const llong2*)(fb + (size_t)(jbase + row) * Dk + chunk * 16);
      *(llong2*)(Bsh + row * Dk + ((chunk ^ (row & 7)) * 16)) = v;
    }
  }

  // column labels for this lane, packed 2 tiles per reg (labels < 100 fit u16)
  int labj16[8];
#pragma unroll
  for (int j = 0; j < 8; ++j) {
    const int l0 = labels[jbase + (2 * j) * 16 + lr];
    const int l1 = labels[jbase + (2 * j + 1) * 16 + lr];
    labj16[j] = l0 | (l1 << 16);
  }

  bool dl[4];
#pragma unroll
  for (int r = 0; r < 4; ++r) dl[r] = (quad * 4 + r) == lr;

  // per-lane swizzled 16B-chunk offsets (constant across jt), in bytes
  const int sw  = lr & 7;
  const int ch0 = ((quad * 2)     ^ sw) * 16;   // k-blocks m=0,1
  const int ch1 = ((quad * 2 + 1) ^ sw) * 16;   // k-blocks m=2,3

  __syncthreads();

#pragma unroll 1
  for (int p = 0; p < 2; ++p) {
    // rows [ibase, ibase+32) this pass; wave covers 64 rows total
    const int ibase = blockIdx.y * 256 + wave * 64 + p * 32;

    // A fragments: per row-tile 32 contiguous bytes (permuted layout)
    intx8 A0, A1;
    {
      const unsigned char* ap0 = fb + (size_t)(ibase + lr) * Dk + quad * 32;
      A0 = *(const intx8*)(ap0);
      A1 = *(const intx8*)(ap0 + 16 * Dk);
    }

    // row labels (accumulator rows: row_in_tile = quad*4 + r)
    int li[2][4];
#pragma unroll
    for (int tt = 0; tt < 2; ++tt)
#pragma unroll
      for (int r = 0; r < 4; ++r)
        li[tt][r] = labels[ibase + tt * 16 + quad * 4 + r];

    float pos[2][4] = {};
    float neg[2][4] = {};

#pragma unroll
    for (int jt = 0; jt < 16; ++jt) {
      const unsigned char* bp = Bsh + (jt * 16 + lr) * Dk;
      const intx4 Blo = *(const intx4*)(bp + ch0);   // k-blocks 0,1
      const intx4 Bhi = *(const intx4*)(bp + ch1);   // k-blocks 2,3
      intx8 Bv;
      Bv[0] = Blo[0]; Bv[1] = Blo[1]; Bv[2] = Blo[2]; Bv[3] = Blo[3];
      Bv[4] = Bhi[0]; Bv[5] = Bhi[1]; Bv[6] = Bhi[2]; Bv[7] = Bhi[3];

      floatx4 acc0 = {0.f, 0.f, 0.f, 0.f};
      floatx4 acc1 = {0.f, 0.f, 0.f, 0.f};
      // cbsz=0 (A fp8 e4m3), blgp=0 (B fp8 e4m3), identity scales
      acc0 = __builtin_amdgcn_mfma_scale_f32_16x16x128_f8f6f4(
          A0, Bv, acc0, 0, 0, 0, SCALE1, 0, SCALE1);
      acc1 = __builtin_amdgcn_mfma_scale_f32_16x16x128_f8f6f4(
          A1, Bv, acc1, 0, 0, 0, SCALE1, 0, SCALE1);

      const int j0 = jbase + jt * 16;
      const int lj = (jt & 1) ? (labj16[jt >> 1] >> 16) : (labj16[jt >> 1] & 0xffff);
      float e0, e1, e2, e3;
      // tile t=0  (C/D layout: col=lane&15, row=quad*4+r — shape-determined)
      e0 = __builtin_amdgcn_exp2f(__builtin_amdgcn_fmed3f(acc0[0], -CLAMP, CLAMP));
      e1 = __builtin_amdgcn_exp2f(__builtin_amdgcn_fmed3f(acc0[1], -CLAMP, CLAMP));
      e2 = __builtin_amdgcn_exp2f(__builtin_amdgcn_fmed3f(acc0[2], -CLAMP, CLAMP));
      e3 = __builtin_amdgcn_exp2f(__builtin_amdgcn_fmed3f(acc0[3], -CLAMP, CLAMP));
      if (j0 == ibase) {                 // wave-uniform: tile on diagonal
        if (dl[0]) e0 = 0.f;
        if (dl[1]) e1 = 0.f;
        if (dl[2]) e2 = 0.f;
        if (dl[3]) e3 = 0.f;
      }
      neg[0][0] += e0; neg[0][1] += e1; neg[0][2] += e2; neg[0][3] += e3;
      pos[0][0] += (li[0][0] == lj) ? e0 : 0.f;
      pos[0][1] += (li[0][1] == lj) ? e1 : 0.f;
      pos[0][2] += (li[0][2] == lj) ? e2 : 0.f;
      pos[0][3] += (li[0][3] == lj) ? e3 : 0.f;
      // tile t=1
      e0 = __builtin_amdgcn_exp2f(__builtin_amdgcn_fmed3f(acc1[0], -CLAMP, CLAMP));
      e1 = __builtin_amdgcn_exp2f(__builtin_amdgcn_fmed3f(acc1[1], -CLAMP, CLAMP));
      e2 = __builtin_amdgcn_exp2f(__builtin_amdgcn_fmed3f(acc1[2], -CLAMP, CLAMP));
      e3 = __builtin_amdgcn_exp2f(__builtin_amdgcn_fmed3f(acc1[3], -CLAMP, CLAMP));
      if (j0 == ibase + 16) {
        if (dl[0]) e0 = 0.f;
        if (dl[1]) e1 = 0.f;
        if (dl[2]) e2 = 0.f;
        if (dl[3]) e3 = 0.f;
      }
      neg[1][0] += e0; neg[1][1] += e1; neg[1][2] += e2; neg[1][3] += e3;
      pos[1][0] += (li[1][0] == lj) ? e0 : 0.f;
      pos[1][1] += (li[1][1] == lj) ? e1 : 0.f;
      pos[1][2] += (li[1][2] == lj) ? e2 : 0.f;
      pos[1][3] += (li[1][3] == lj) ? e3 : 0.f;
    }

    // reduce across the 16 lanes of a col-group (xor 1,2,4,8 stays in group);
    // unique (slice,row) writer -> plain stores, no atomics, no memset
#pragma unroll
    for (int tt = 0; tt < 2; ++tt)
#pragma unroll
      for (int r = 0; r < 4; ++r) {
        float p2 = pos[tt][r], n2 = neg[tt][r];
#pragma unroll
        for (int m = 1; m < 16; m <<= 1) {
          p2 += __shfl_xor(p2, m);
          n2 += __shfl_xor(n2, m);
        }
        if (lr == 0) {
          const int row = ibase + tt * 16 + quad * 4 + r;
          rowpos2[(size_t)blockIdx.x * Bn + row] = p2;
          rowneg2[(size_t)blockIdx.x * Bn + row] = n2;
        }
      }

    __builtin_amdgcn_sched_barrier(0);   // keep pass-1 A-loads from hoisting
  }
}

// ---- kernel 3: sum slice partials, per-row loss, mean (distributed) ------
__global__ __launch_bounds__(256) void finalize_k(
    const float* __restrict__ rowpos2, const float* __restrict__ rowneg2,
    float* __restrict__ out) {
  const int row = blockIdx.x * 256 + threadIdx.x;
  float p = 0.f, n = 0.f;
#pragma unroll
  for (int s = 0; s < NSLICE; ++s) {       // coalesced: consecutive rows adjacent
    p += rowpos2[(size_t)s * Bn + row];
    n += rowneg2[(size_t)s * Bn + row];
  }
  p = fmaxf(p, 1e-8f);
  n = fmaxf(n, 1e-8f);
  float loss = LN2 * (__builtin_amdgcn_logf(n) - __builtin_amdgcn_logf(p));
#pragma unroll
  for (int m = 1; m < 64; m <<= 1) loss += __shfl_xor(loss, m);
  __shared__ float partial[4];
  const int lane = threadIdx.x & 63, w = threadIdx.x >> 6;
  if (lane == 0) partial[w] = loss;
  __syncthreads();
  if (threadIdx.x == 0) {
    const float s = partial[0] + partial[1] + partial[2] + partial[3];
    atomicAdd(out, s * (1.0f / (float)Bn));   // out zeroed by normalize_k
  }
}

extern "C" void kernel_launch(void* const* d_in, const int* in_sizes, int n_in,
                              void* d_out, int out_size, void* d_ws, size_t ws_size,
                              hipStream_t stream) {
  const float* feat   = (const float*)d_in[0];
  const int*   labels = (const int*)d_in[1];
  float* out = (float*)d_out;

  // ws layout: [0, 1MB) fp8 fb[8192][128]; then rowpos2[32][8192], rowneg2[32][8192]
  unsigned char* fb = (unsigned char*)d_ws;
  float* rowpos2 = (float*)((char*)d_ws + (size_t)Bn * Dk);
  float* rowneg2 = rowpos2 + (size_t)NSLICE * Bn;

  normalize_k<<<Bn / 4, 256, 0, stream>>>(feat, fb, out);
  dim3 grid(NSLICE, 32);  // x = j-slice (256 cols), y = i-block (256 rows)
  simloss_k<<<grid, 256, 0, stream>>>(fb, labels, rowpos2, rowneg2);
  finalize_k<<<Bn / 256, 256, 0, stream>>>(rowpos2, rowneg2, out);
}

// Round 12
// 96.585 us; speedup vs baseline: 1.3314x; 1.0301x over previous
//
#include <hip/hip_runtime.h>
#include <hip/hip_bf16.h>

// ContrastiveLoss: B=8192, D=128, 100 classes.
// loss_i = -log( max(sum_{j!=i, lab_j==lab_i} e^{s_ij},1e-8) / max(sum_{j!=i} e^{s_ij},1e-8) )
// s_ij = clip( f_hat_i . f_hat_j / 0.07, -10, 10 );  out = mean_i loss_i
//
// fb = f_hat * sqrt(log2e/0.07) in FP8 e4m3 -> MFMA dot yields s/0.07*log2e;
// clamp +-10*log2e (fmed3), one v_exp_f32. Diagonal zeroed exactly (wave-
// uniform tile check). 2x mfma_scale_f32_16x16x128_f8f6f4 w/ identity scales
// per tile-pair (MX path = 2x fp8 rate, one inst covers K=128; R10 verified).
//
// R11: dispatch-count attack. finalize_k is gone: simloss blocks atomicAdd
// pos/neg partials into rowpos/rowneg (131k f32 atomics, negligible), and the
// LAST block (device-scope done counter + threadfence release/acquire) runs
// the 8192-row log-reduction inline and writes *out. normalize_k zeros
// rowpos/rowneg/done. 3 dispatches -> 2, saves a launch gap + 4 MB of
// slice-partial traffic. The done-flag broadcast reuses Bsh (dead after the
// main loop) to keep LDS at exactly 32768 B.

using floatx4 = __attribute__((ext_vector_type(4))) float;
using intx4   = __attribute__((ext_vector_type(4))) int;
using intx8   = __attribute__((ext_vector_type(8))) int;
using llong2  = __attribute__((ext_vector_type(2))) long long;

constexpr int   Bn = 8192;
constexpr int   Dk = 128;                  // bytes per fp8 row
constexpr int   NSLICE = 32;               // j-slices (blockIdx.x), 256 cols each
constexpr int   NBLK   = 32 * 32;          // simloss grid size
constexpr float PRESCALE = 4.5398160f;     // sqrt(log2(e)/0.07)
constexpr float CLAMP    = 14.4269504f;    // 10*log2(e)
constexpr float LN2      = 0.69314718056f;
constexpr int   SCALE1   = 0x7F7F7F7F;     // identity E8M0 scale for 4 k-blocks

// ---- kernel 1: L2-normalize, scale, cast fp8, k-permuted store ----------
// permutation: byte position p(k) = ((k%32)/8)*32 + (k/32)*8 + (k%8), so a
// lane's MFMA operands (k = m*32 + quad*8 + j, m=0..3) are 32 contiguous
// bytes at offset quad*32 (matches the f8f6f4 stacked-K=32 operand layout).
// Also zeros rowpos/rowneg/done for the simloss atomics.
__global__ __launch_bounds__(256) void normalize_k(
    const float* __restrict__ feat, unsigned char* __restrict__ fb,
    float* __restrict__ rowpos, float* __restrict__ rowneg,
    unsigned int* __restrict__ done) {
  if (blockIdx.x < 32) {
    rowpos[blockIdx.x * 256 + threadIdx.x] = 0.f;
    rowneg[blockIdx.x * 256 + threadIdx.x] = 0.f;
  }
  if (blockIdx.x == 32 && threadIdx.x == 0) *done = 0u;
  const int row  = blockIdx.x * 4 + (threadIdx.x >> 6);
  const int lane = threadIdx.x & 63;
  const float2 v = ((const float2*)(feat + (size_t)row * Dk))[lane];
  float s = v.x * v.x + v.y * v.y;
#pragma unroll
  for (int m = 1; m < 64; m <<= 1) s += __shfl_xor(s, m);
  const float inv = PRESCALE / fmaxf(sqrtf(s), 1e-8f);
  const int packed = __builtin_amdgcn_cvt_pk_fp8_f32(v.x * inv, v.y * inv, 0, false);
  const int k0 = 2 * lane;   // k0 even -> both bytes land adjacent after permute
  const int p  = ((k0 & 31) >> 3) * 32 + (k0 >> 5) * 8 + (k0 & 7);
  *(unsigned short*)(fb + (size_t)row * Dk + p) = (unsigned short)(packed & 0xffff);
}

// ---- kernel 2: tiled F*F^T + fused exp + masked row-sum + inline tail ----
// grid: (32 j-slices, 32 i-blocks). Block = 256 thr = 4 waves, 32 KB LDS.
// Block stages its 256-col fp8 B panel (XOR-16B-chunk swizzle); each wave
// covers 64 rows as two sequential 32-row passes x 256 cols (16 tiles).
__global__ __launch_bounds__(256, 2) void simloss_k(
    const unsigned char* __restrict__ fb, const int* __restrict__ labels,
    float* __restrict__ rowpos, float* __restrict__ rowneg,
    unsigned int* __restrict__ done, float* __restrict__ out) {
  __shared__ __align__(16) unsigned char Bsh[256 * Dk];   // 32768 B

  const int t     = threadIdx.x;
  const int lane  = t & 63;
  const int wave  = t >> 6;                         // [0,4)
  const int quad  = lane >> 4;
  const int lr    = lane & 15;
  const int jbase = blockIdx.x * 256;               // cols [jbase, jbase+256)

  // ---- stage B panel: 16B chunk c of row r -> LDS chunk c ^ (r&7) --------
  {
    const int chunk = t & 7;         // 16B chunk within a 128B row
    const int r0    = t >> 3;        // [0,32)
#pragma unroll
    for (int it = 0; it < 8; ++it) {
      const int row = r0 + it * 32;
      const llong2 v = *(const llong2*)(fb + (size_t)(jbase + row) * Dk + chunk * 16);
      *(llong2*)(Bsh + row * Dk + ((chunk ^ (row & 7)) * 16)) = v;
    }
  }

  // column labels for this lane, packed 2 tiles per reg (labels < 100 fit u16)
  int labj16[8];
#pragma unroll
  for (int j = 0; j < 8; ++j) {
    const int l0 = labels[jbase + (2 * j) * 16 + lr];
    const int l1 = labels[jbase + (2 * j + 1) * 16 + lr];
    labj16[j] = l0 | (l1 << 16);
  }

  bool dl[4];
#pragma unroll
  for (int r = 0; r < 4; ++r) dl[r] = (quad * 4 + r) == lr;

  // per-lane swizzled 16B-chunk offsets (constant across jt), in bytes
  const int sw  = lr & 7;
  const int ch0 = ((quad * 2)     ^ sw) * 16;   // k-blocks m=0,1
  const int ch1 = ((quad * 2 + 1) ^ sw) * 16;   // k-blocks m=2,3

  __syncthreads();

#pragma unroll 1
  for (int p = 0; p < 2; ++p) {
    // rows [ibase, ibase+32) this pass; wave covers 64 rows total
    const int ibase = blockIdx.y * 256 + wave * 64 + p * 32;

    // A fragments: per row-tile 32 contiguous bytes (permuted layout)
    intx8 A0, A1;
    {
      const unsigned char* ap0 = fb + (size_t)(ibase + lr) * Dk + quad * 32;
      A0 = *(const intx8*)(ap0);
      A1 = *(const intx8*)(ap0 + 16 * Dk);
    }

    // row labels (accumulator rows: row_in_tile = quad*4 + r)
    int li[2][4];
#pragma unroll
    for (int tt = 0; tt < 2; ++tt)
#pragma unroll
      for (int r = 0; r < 4; ++r)
        li[tt][r] = labels[ibase + tt * 16 + quad * 4 + r];

    float pos[2][4] = {};
    float neg[2][4] = {};

#pragma unroll
    for (int jt = 0; jt < 16; ++jt) {
      const unsigned char* bp = Bsh + (jt * 16 + lr) * Dk;
      const intx4 Blo = *(const intx4*)(bp + ch0);   // k-blocks 0,1
      const intx4 Bhi = *(const intx4*)(bp + ch1);   // k-blocks 2,3
      intx8 Bv;
      Bv[0] = Blo[0]; Bv[1] = Blo[1]; Bv[2] = Blo[2]; Bv[3] = Blo[3];
      Bv[4] = Bhi[0]; Bv[5] = Bhi[1]; Bv[6] = Bhi[2]; Bv[7] = Bhi[3];

      floatx4 acc0 = {0.f, 0.f, 0.f, 0.f};
      floatx4 acc1 = {0.f, 0.f, 0.f, 0.f};
      // cbsz=0 (A fp8 e4m3), blgp=0 (B fp8 e4m3), identity scales
      acc0 = __builtin_amdgcn_mfma_scale_f32_16x16x128_f8f6f4(
          A0, Bv, acc0, 0, 0, 0, SCALE1, 0, SCALE1);
      acc1 = __builtin_amdgcn_mfma_scale_f32_16x16x128_f8f6f4(
          A1, Bv, acc1, 0, 0, 0, SCALE1, 0, SCALE1);

      const int j0 = jbase + jt * 16;
      const int lj = (jt & 1) ? (labj16[jt >> 1] >> 16) : (labj16[jt >> 1] & 0xffff);
      float e0, e1, e2, e3;
      // tile t=0  (C/D layout: col=lane&15, row=quad*4+r — shape-determined)
      e0 = __builtin_amdgcn_exp2f(__builtin_amdgcn_fmed3f(acc0[0], -CLAMP, CLAMP));
      e1 = __builtin_amdgcn_exp2f(__builtin_amdgcn_fmed3f(acc0[1], -CLAMP, CLAMP));
      e2 = __builtin_amdgcn_exp2f(__builtin_amdgcn_fmed3f(acc0[2], -CLAMP, CLAMP));
      e3 = __builtin_amdgcn_exp2f(__builtin_amdgcn_fmed3f(acc0[3], -CLAMP, CLAMP));
      if (j0 == ibase) {                 // wave-uniform: tile on diagonal
        if (dl[0]) e0 = 0.f;
        if (dl[1]) e1 = 0.f;
        if (dl[2]) e2 = 0.f;
        if (dl[3]) e3 = 0.f;
      }
      neg[0][0] += e0; neg[0][1] += e1; neg[0][2] += e2; neg[0][3] += e3;
      pos[0][0] += (li[0][0] == lj) ? e0 : 0.f;
      pos[0][1] += (li[0][1] == lj) ? e1 : 0.f;
      pos[0][2] += (li[0][2] == lj) ? e2 : 0.f;
      pos[0][3] += (li[0][3] == lj) ? e3 : 0.f;
      // tile t=1
      e0 = __builtin_amdgcn_exp2f(__builtin_amdgcn_fmed3f(acc1[0], -CLAMP, CLAMP));
      e1 = __builtin_amdgcn_exp2f(__builtin_amdgcn_fmed3f(acc1[1], -CLAMP, CLAMP));
      e2 = __builtin_amdgcn_exp2f(__builtin_amdgcn_fmed3f(acc1[2], -CLAMP, CLAMP));
      e3 = __builtin_amdgcn_exp2f(__builtin_amdgcn_fmed3f(acc1[3], -CLAMP, CLAMP));
      if (j0 == ibase + 16) {
        if (dl[0]) e0 = 0.f;
        if (dl[1]) e1 = 0.f;
        if (dl[2]) e2 = 0.f;
        if (dl[3]) e3 = 0.f;
      }
      neg[1][0] += e0; neg[1][1] += e1; neg[1][2] += e2; neg[1][3] += e3;
      pos[1][0] += (li[1][0] == lj) ? e0 : 0.f;
      pos[1][1] += (li[1][1] == lj) ? e1 : 0.f;
      pos[1][2] += (li[1][2] == lj) ? e2 : 0.f;
      pos[1][3] += (li[1][3] == lj) ? e3 : 0.f;
    }

    // reduce across the 16 lanes of a col-group (xor 1,2,4,8 stays in group),
    // then one atomicAdd per row into the global accumulators
#pragma unroll
    for (int tt = 0; tt < 2; ++tt)
#pragma unroll
      for (int r = 0; r < 4; ++r) {
        float p2 = pos[tt][r], n2 = neg[tt][r];
#pragma unroll
        for (int m = 1; m < 16; m <<= 1) {
          p2 += __shfl_xor(p2, m);
          n2 += __shfl_xor(n2, m);
        }
        if (lr == 0) {
          const int row = ibase + tt * 16 + quad * 4 + r;
          atomicAdd(&rowpos[row], p2);
          atomicAdd(&rowneg[row], n2);
        }
      }

    __builtin_amdgcn_sched_barrier(0);   // keep pass-1 A-loads from hoisting
  }

  // ---- inline finalize: last block to finish reduces rowpos/rowneg ------
  __syncthreads();                       // drains this block's atomics (vmcnt)
  int* flag = (int*)Bsh;                 // Bsh is dead; reuse as broadcast flag
  if (t == 0) {
    __threadfence();                     // release: make atomics visible
    const unsigned int old = atomicAdd(done, 1u);
    *flag = (old == (unsigned)(NBLK - 1)) ? 1 : 0;
  }
  __syncthreads();
  if (*flag) {
    __threadfence();                     // acquire: see all blocks' atomics
    float acc = 0.f;
#pragma unroll
    for (int r = 0; r < Bn / 256; ++r) {
      const int row = r * 256 + t;
      const float pp = fmaxf(rowpos[row], 1e-8f);
      const float nn = fmaxf(rowneg[row], 1e-8f);
      acc += __builtin_amdgcn_logf(nn) - __builtin_amdgcn_logf(pp);
    }
#pragma unroll
    for (int m = 1; m < 64; m <<= 1) acc += __shfl_xor(acc, m);
    float* red = (float*)Bsh + 16;
    if (lane == 0) red[wave] = acc;
    __syncthreads();
    if (t == 0)
      *out = (red[0] + red[1] + red[2] + red[3]) * (LN2 / (float)Bn);
  }
}

extern "C" void kernel_launch(void* const* d_in, const int* in_sizes, int n_in,
                              void* d_out, int out_size, void* d_ws, size_t ws_size,
                              hipStream_t stream) {
  const float* feat   = (const float*)d_in[0];
  const int*   labels = (const int*)d_in[1];
  float* out = (float*)d_out;

  // ws layout: [0, 1MB) fp8 fb[8192][128]; rowpos[8192]; rowneg[8192]; done
  unsigned char* fb = (unsigned char*)d_ws;
  float* rowpos = (float*)((char*)d_ws + (size_t)Bn * Dk);
  float* rowneg = rowpos + Bn;
  unsigned int* done = (unsigned int*)(rowneg + Bn);

  normalize_k<<<Bn / 4, 256, 0, stream>>>(feat, fb, rowpos, rowneg, done);
  dim3 grid(NSLICE, 32);  // x = j-slice (256 cols), y = i-block (256 rows)
  simloss_k<<<grid, 256, 0, stream>>>(fb, labels, rowpos, rowneg, done, out);
}